// Round 12
// baseline (152.361 us; speedup 1.0000x reference)
//
#include <hip/hip_runtime.h>
#include <hip/hip_bf16.h>
#include <math.h>

#define B_DIM 8
#define C_DIM 32
#define N_DIM 4096
#define KSL 1024             // k per kq-subgroup
#define NCH (KSL / 32)       // 32 chunks per wave
#define PART_ELEMS (B_DIM * C_DIM * N_DIM)   // 1,048,576 f32 per K-half

typedef short bf16x8 __attribute__((ext_vector_type(8)));   // 8 bf16 = 4 VGPRs
typedef float f32x4 __attribute__((ext_vector_type(4)));
typedef unsigned int uint4v __attribute__((ext_vector_type(4)));

__device__ __forceinline__ ushort f2bf_rne(float f) {
  unsigned u = __float_as_uint(f);
  u += 0x7FFF + ((u >> 16) & 1);
  return (ushort)(u >> 16);
}

// Fused prep (verified): one pass over x -> E[b,n] = exp(mean_c x) and
// tiled bf16 feabT[((b*128 + n/32)*32 + c)*32 + n%32].
__global__ __launch_bounds__(256) void prep_fused(const float* __restrict__ x,
                                                  float* __restrict__ E,
                                                  ushort* __restrict__ feabT) {
  int idx = blockIdx.x * 256 + threadIdx.x;   // 0 .. B*N-1
  int b = idx >> 12;
  int n = idx & (N_DIM - 1);
  const float* p = x + (size_t)b * C_DIM * N_DIM + n;
  ushort* q = feabT + ((size_t)(b * (N_DIM / 32) + (n >> 5)) * C_DIM) * 32 + (n & 31);
  float s = 0.f;
#pragma unroll
  for (int c = 0; c < C_DIM; ++c) {
    float v = p[(size_t)c * N_DIM];
    s += v;
    q[c * 32] = f2bf_rne(v);
  }
  E[idx] = __builtin_amdgcn_exp2f(s * (1.44269504f / C_DIM));
}

// K-split GCN main kernel.
//   Evidence r0..r11: every single-barrier-group structure (0/16/128
//   barriers alike) pins at VALUBusy 36-45%, 2300-3500 cyc/chunk -- with one
//   16-wave group and 4 waves/SIMD, all waves hit the same dependency points
//   together; ~55% of cycles nothing issues.  Fix: TWO independent blocks
//   per CU at UNCHANGED 1x adj traffic (the r3 trap was batch-split blocks
//   re-reading the same adj rows; a K-split's blocks read DISJOINT rows).
//   grid = 512 = 256 colgrps x 2 K-halves; block = 1024 thr = 8 batches x
//   2 kq-subgroups -> 2 blocks/CU, 32 waves/CU (max).  Chunk body is r0's
//   measured-best form verbatim: per-chunk cooperative staging (1 dword/thr),
//   depth-2 register pipeline, 2 plain __syncthreads/chunk, stride-33 LDS.
//   Cross-block combine via part[2] in ws (+epilogue kernel).
__global__ __launch_bounds__(1024, 8) void gcn_part(
    const ushort* __restrict__ feabT, const float* __restrict__ adj,
    const float* __restrict__ E, float* __restrict__ part) {
  __shared__ float abuf[2][32 * 33 + 4];   // per-subgroup tile, stride 33
  __shared__ float red[B_DIM][544];        // stride 17, 17.4 KB

  const int tid = threadIdx.x;
  const int lane = tid & 63;
  const int w = tid >> 6;           // 0..15
  const int b = w & 7;              // batch
  const int sub = w >> 3;           // 0..1 kq-subgroup
  const int quad = lane >> 4;
  const int l15 = lane & 15;
  const int bid = blockIdx.x;
  const int colgrp = bid & 255;
  const int khp = bid >> 8;         // 0..1 K-half (this block's output slot)
  const int col = colgrp * 16 + l15;
  const int kq = khp * 2 + sub;     // 0..3 K-quarter of this wave
  const int ksbase = kq * KSL;

  // staging: each subgroup's 512 threads cover its 32x16 tile, 1 elem each
  const int tg = tid & 511;
  const float* agp = adj + (size_t)(ksbase + (tg >> 4)) * N_DIM + colgrp * 16 + (tg & 15);
  const int swaddr = (tg >> 4) * 33 + (tg & 15);

  const float* Eb = E + (size_t)b * N_DIM;
  const float Em = Eb[col];
  const float* ekb = Eb + ksbase + quad * 8;
  const ushort* fb = feabT + ((size_t)(b * (N_DIM / 32) + (ksbase >> 5))) * (C_DIM * 32);

  f32x4 acc0 = {0.f, 0.f, 0.f, 0.f};   // channels 0-15
  f32x4 acc1 = {0.f, 0.f, 0.f, 0.f};   // channels 16-31

  // depth-2 adj register staging pipeline (r0 structure, x2 folded out)
  float a_nxt = agp[0];
  float a_nx2 = agp[(size_t)32 * N_DIM];
  abuf[sub][swaddr] = a_nxt;
  a_nxt = a_nx2;
  __syncthreads();

  for (int ch = 0; ch < NCH; ++ch) {
    // issue tile ch+2's staging load now (~2 chunks of distance to its use)
    if (ch + 2 < NCH) a_nx2 = agp[(size_t)(ch + 2) * 32 * N_DIM];

    // fea fragments + E k-values for this wave's batch
    const ushort* tile = fb + (size_t)ch * (C_DIM * 32);
    const bf16x8 fa0 = *(const bf16x8*)(tile + l15 * 32 + quad * 8);
    const bf16x8 fa1 = *(const bf16x8*)(tile + (16 + l15) * 32 + quad * 8);
    float ekv[8];
    *(f32x4*)&ekv[0] = *(const f32x4*)(ekb + ch * 32);
    *(f32x4*)&ekv[4] = *(const f32x4*)(ekb + ch * 32 + 4);

    // adj fragment from this subgroup's LDS tile (shared by its 8 batches)
    float a2[8];
#pragma unroll
    for (int j = 0; j < 8; ++j) a2[j] = abuf[sub][(quad * 8 + j) * 33 + l15];

    // w = adj * min(Ek,Em) * rcp(Ek+Em); pairwise-shared rcp (x2 in epilogue)
    uint4v wfu;
#pragma unroll
    for (int p = 0; p < 4; ++p) {
      const float e0 = ekv[2 * p];
      const float e1 = ekv[2 * p + 1];
      const float t0 = fminf(e0, Em);
      const float t1 = fminf(e1, Em);
      const float s0 = e0 + Em;
      const float s1 = e1 + Em;
      const float r = __builtin_amdgcn_rcpf(s0 * s1);
      const float w0 = a2[2 * p] * t0 * (r * s1);
      const float w1 = a2[2 * p + 1] * t1 * (r * s0);
      // truncating bf16x2 pack: bytes [w0.b2, w0.b3, w1.b2, w1.b3]
      wfu[p] = __builtin_amdgcn_perm(__float_as_uint(w1), __float_as_uint(w0),
                                     0x07060302u);
    }
    const bf16x8 wf = __builtin_bit_cast(bf16x8, wfu);

    acc0 = __builtin_amdgcn_mfma_f32_16x16x32_bf16(fa0, wf, acc0, 0, 0, 0);
    acc1 = __builtin_amdgcn_mfma_f32_16x16x32_bf16(fa1, wf, acc1, 0, 0, 0);

    __syncthreads();   // subgroup done reading its abuf tile for chunk ch
    if (ch + 1 < NCH) {
      abuf[sub][swaddr] = a_nxt;   // value loaded >=1 full chunk ago
      a_nxt = a_nx2;
    }
    __syncthreads();   // staged writes visible
  }

  // in-block kq-subgroup reduce, then write this K-half's partial
  if (sub == 1) {
#pragma unroll
    for (int r = 0; r < 4; ++r) {
      red[b][(quad * 4 + r) * 17 + l15] = acc0[r];
      red[b][(16 + quad * 4 + r) * 17 + l15] = acc1[r];
    }
  }
  __syncthreads();
  if (sub == 0) {
#pragma unroll
    for (int r = 0; r < 4; ++r) {
      const int c0 = quad * 4 + r;
      const int c1 = c0 + 16;
      const float s0 = acc0[r] + red[b][c0 * 17 + l15];
      const float s1 = acc1[r] + red[b][c1 * 17 + l15];
      part[(size_t)khp * PART_ELEMS + ((size_t)(b * C_DIM + c0)) * N_DIM + col] = s0;
      part[(size_t)khp * PART_ELEMS + ((size_t)(b * C_DIM + c1)) * N_DIM + col] = s1;
    }
  }
}

// out = relu((part0 + part1) * 2 * para); ~12.5 MB traffic, f32x4 vectorized
__global__ __launch_bounds__(256) void epilogue(const float* __restrict__ part,
                                                const float* __restrict__ para,
                                                float* __restrict__ out) {
  const size_t off = ((size_t)blockIdx.x * 256 + threadIdx.x) * 4;
  const size_t cm = off & ((size_t)C_DIM * N_DIM - 1);   // [c][m] within batch
  const f32x4 p0 = *(const f32x4*)(part + off);
  const f32x4 p1 = *(const f32x4*)(part + PART_ELEMS + off);
  const f32x4 pr = *(const f32x4*)(para + cm);
  f32x4 o;
#pragma unroll
  for (int i = 0; i < 4; ++i) o[i] = fmaxf((p0[i] + p1[i]) * 2.0f * pr[i], 0.f);
  *(f32x4*)(out + off) = o;
}

extern "C" void kernel_launch(void* const* d_in, const int* in_sizes, int n_in,
                              void* d_out, int out_size, void* d_ws, size_t ws_size,
                              hipStream_t stream) {
  const float* x = (const float*)d_in[0];     // [8,32,64,64]
  const float* para = (const float*)d_in[1];  // [1,32,64,64]
  const float* adj = (const float*)d_in[2];   // [4096,4096]
  float* out = (float*)d_out;

  // ws: E (128 KB) | feabT (2 MB) | part (8 MB) -- 10.125 MB total
  float* E = (float*)d_ws;
  ushort* feabT = (ushort*)(E + (size_t)B_DIM * N_DIM);
  float* part = (float*)(feabT + (size_t)B_DIM * C_DIM * N_DIM);

  prep_fused<<<dim3(B_DIM * N_DIM / 256), dim3(256), 0, stream>>>(x, E, feabT);
  gcn_part<<<dim3(512), dim3(1024), 0, stream>>>(feabT, adj, E, part);
  epilogue<<<dim3(PART_ELEMS / 4 / 256), dim3(256), 0, stream>>>(part, para, out);
}